// Round 1
// baseline (94.066 us; speedup 1.0000x reference)
//
#include <hip/hip_runtime.h>
#include <hip/hip_bf16.h>

#define D_ 256
#define HW_ 1024
#define NPTS 65536
#define K_ 1024

typedef short short8 __attribute__((ext_vector_type(8)));
typedef float float4v __attribute__((ext_vector_type(4)));

__device__ __forceinline__ unsigned short f2bf(float f) {
  unsigned u = __builtin_bit_cast(unsigned, f);
  return (unsigned short)((u + 0x7fffu + ((u >> 16) & 1u)) >> 16);
}

__device__ __forceinline__ void async16(void* lds, const void* g) {
  __builtin_amdgcn_global_load_lds(
      (__attribute__((address_space(1))) const unsigned int*)g,
      (__attribute__((address_space(3))) unsigned int*)lds, 16, 0, 0);
}

// ---------------- prep: cnorm + bf16(-2c) swizzled chunk image ----------------
// image layout: chunk c (128 codes) -> rows row=k&127 of 512B; byte for feature d
// stored at (2d) ^ ((row&15)<<5)  [conflict-free ds_read_b128 swizzle]
__global__ __launch_bounds__(256) void vq_prep(const float* __restrict__ cb,
                                               unsigned short* __restrict__ cbimg,
                                               float* __restrict__ cnorm) {
  int k = blockIdx.x;   // 0..1023
  int t = threadIdx.x;  // 0..255
  float c = cb[k * D_ + t];
  float s = c * c;
#pragma unroll
  for (int off = 1; off < 64; off <<= 1) s += __shfl_xor(s, off, 64);
  __shared__ float wsum[4];
  if ((t & 63) == 0) wsum[t >> 6] = s;
  __syncthreads();
  if (t == 0) cnorm[k] = wsum[0] + wsum[1] + wsum[2] + wsum[3];
  int row = k & 127, chunk = k >> 7;
  unsigned short bv = f2bf(-2.0f * c);
  int byteoff = (2 * t) ^ ((row & 15) << 5);
  *(unsigned short*)((char*)cbimg + chunk * 65536 + row * 512 + byteoff) = bv;
}

// ---------------- main: distances + argmin + loss partials ----------------
// block: 512 thr = 8 waves. wave w: point-group pg=w&3 (64 pts), code-half ch=w>>2.
// Points (B-operand) live in registers: bfrag[pf][kk]. Codebook chunks (128 codes
// = 64KB) double-buffered in LDS via global_load_lds from the pre-swizzled image.
__global__ __launch_bounds__(512, 2) void vq_main(const float* __restrict__ lat,
                                                  const short8* __restrict__ cbimg,
                                                  const float* __restrict__ cnorm,
                                                  int* __restrict__ idx_out,
                                                  float* __restrict__ part) {
  __shared__ short8 cbA[2][4096];   // 2 x 64KB
  __shared__ float cnorm_s[1024];
  __shared__ float mergeD[256];
  __shared__ int mergeI[256];

  const int tid = threadIdx.x;
  const int w = tid >> 6, lane = tid & 63;
  const int pg = w & 3, ch = w >> 2;
  const int q = lane >> 4, c = lane & 15;
  const int pt0 = blockIdx.x * 256;
  const int b = pt0 >> 10, hw0 = pt0 & 1023;

  cnorm_s[tid] = cnorm[tid];
  cnorm_s[tid + 512] = cnorm[tid + 512];

  // prefetch chunk 0 into buf 0 (linear copy of pre-swizzled image)
#pragma unroll
  for (int r = 0; r < 8; ++r)
    async16(&cbA[0][r * 512 + tid], cbimg + (r * 512 + tid));

  // stage points into registers (B-frags), fp32->bf16, and per-point |f|^2
  short8 bfrag[4][8];
  float fn[4];
  const int hwp_base = hw0 + pg * 64 + c;
#pragma unroll
  for (int pf = 0; pf < 4; ++pf) {
    int hwp = hwp_base + pf * 16;
    float a = 0.f;
#pragma unroll
    for (int kk = 0; kk < 8; ++kk) {
      short8 v;
#pragma unroll
      for (int j = 0; j < 8; ++j) {
        int d = kk * 32 + q * 8 + j;
        float f = lat[(b * D_ + d) * HW_ + hwp];
        a += f * f;
        v[j] = (short)f2bf(f);
      }
      bfrag[pf][kk] = v;
    }
    fn[pf] = a;
  }
#pragma unroll
  for (int pf = 0; pf < 4; ++pf) {
    fn[pf] += __shfl_xor(fn[pf], 16, 64);
    fn[pf] += __shfl_xor(fn[pf], 32, 64);
  }

  __syncthreads();  // chunk0 loaded, cnorm_s ready

  float runD[4];
  int runI[4];
#pragma unroll
  for (int pf = 0; pf < 4; ++pf) { runD[pf] = 3.0e38f; runI[pf] = 0x7fffffff; }

  int buf = 0;
  for (int chunk = 0; chunk < 8; ++chunk) {
    if (chunk < 7) {
#pragma unroll
      for (int r = 0; r < 8; ++r)
        async16(&cbA[buf ^ 1][r * 512 + tid],
                cbimg + ((chunk + 1) * 4096 + r * 512 + tid));
    }
    // acc init = cnorm[code]  (codebook image is -2c, so MFMA yields dist directly)
    float4v acc[4][4];
#pragma unroll
    for (int af = 0; af < 4; ++af) {
      int cb0 = chunk * 128 + ch * 64 + af * 16 + q * 4;
      float4v cn;
      cn[0] = cnorm_s[cb0]; cn[1] = cnorm_s[cb0 + 1];
      cn[2] = cnorm_s[cb0 + 2]; cn[3] = cnorm_s[cb0 + 3];
#pragma unroll
      for (int pf = 0; pf < 4; ++pf) acc[af][pf] = cn;
    }
    const int rowbase = (ch * 64 + c) * 32;  // short8 units
#pragma unroll
    for (int kk = 0; kk < 8; ++kk) {
      short8 a[4];
#pragma unroll
      for (int af = 0; af < 4; ++af)
        a[af] = cbA[buf][rowbase + af * 512 + (((kk << 2) | q) ^ (c << 1))];
#pragma unroll
      for (int af = 0; af < 4; ++af)
#pragma unroll
        for (int pf = 0; pf < 4; ++pf)
          acc[af][pf] = __builtin_amdgcn_mfma_f32_16x16x32_bf16(
              a[af], bfrag[pf][kk], acc[af][pf], 0, 0, 0);
    }
    // argmin epilogue (first-occurrence tie-break, matching np.argmin)
#pragma unroll
    for (int pf = 0; pf < 4; ++pf) {
      float md = 3.0e38f;
      int mi = 0x7fffffff;
#pragma unroll
      for (int af = 0; af < 4; ++af) {
        int cb0 = chunk * 128 + ch * 64 + af * 16 + q * 4;
#pragma unroll
        for (int r = 0; r < 4; ++r) {
          float dv = acc[af][pf][r];
          if (dv < md) { md = dv; mi = cb0 + r; }
        }
      }
#pragma unroll
      for (int di = 16; di < 64; di <<= 1) {
        float od = __shfl_xor(md, di, 64);
        int oi = __shfl_xor(mi, di, 64);
        if (od < md || (od == md && oi < mi)) { md = od; mi = oi; }
      }
      if (md < runD[pf] || (md == runD[pf] && mi < runI[pf])) {
        runD[pf] = md; runI[pf] = mi;
      }
    }
    __syncthreads();
    buf ^= 1;
  }

  // lane's assigned point: p = pg*64 + lane, uses pair pf==q
  float selD = q == 0 ? runD[0] : q == 1 ? runD[1] : q == 2 ? runD[2] : runD[3];
  int selI = q == 0 ? runI[0] : q == 1 ? runI[1] : q == 2 ? runI[2] : runI[3];
  float selF = q == 0 ? fn[0] : q == 1 ? fn[1] : q == 2 ? fn[2] : fn[3];
  int p = pg * 64 + lane;
  if (ch == 0) { mergeD[p] = selD; mergeI[p] = selI; }
  __syncthreads();
  if (ch == 1) {
    float od = mergeD[p];
    int oi = mergeI[p];
    if (od < selD || (od == selD && oi < selI)) { selD = od; selI = oi; }
    idx_out[pt0 + p] = selI;
    float lv = selD + selF;  // ||f - c_best||^2
#pragma unroll
    for (int off = 1; off < 64; off <<= 1) lv += __shfl_xor(lv, off, 64);
    if (lane == 0) part[blockIdx.x * 4 + pg] = lv;  // deterministic partials
  }
}

// ---------------- gather: out[b,d,h,w] = codebook[idx[n]][d] ----------------
__global__ __launch_bounds__(256) void vq_gather(const float* __restrict__ cb,
                                                 const int* __restrict__ idx,
                                                 float* __restrict__ out) {
  __shared__ float qv[64][257];
  __shared__ int sidx[64];
  int t = threadIdx.x;
  int pt0 = blockIdx.x * 64;
  int b = pt0 >> 10, hw0 = pt0 & 1023;
  if (t < 64) sidx[t] = idx[pt0 + t];
  __syncthreads();
  for (int p = 0; p < 64; ++p) qv[p][t] = cb[sidx[p] * D_ + t];
  __syncthreads();
  int hw = t & 63, dg = t >> 6;
#pragma unroll
  for (int dd = 0; dd < 64; ++dd) {
    int d = dg * 64 + dd;
    out[(b * D_ + d) * HW_ + hw0 + hw] = qv[hw][d];
  }
}

// ---------------- finalize: loss = 1.25 * mean ----------------
__global__ __launch_bounds__(256) void vq_fin(const float* __restrict__ part,
                                              float* __restrict__ outs) {
  int t = threadIdx.x;
  float s = part[t] + part[t + 256] + part[t + 512] + part[t + 768];
#pragma unroll
  for (int off = 1; off < 64; off <<= 1) s += __shfl_xor(s, off, 64);
  __shared__ float w4[4];
  if ((t & 63) == 0) w4[t >> 6] = s;
  __syncthreads();
  if (t == 0) *outs = (w4[0] + w4[1] + w4[2] + w4[3]) * (1.25f / 16777216.0f);
}

extern "C" void kernel_launch(void* const* d_in, const int* in_sizes, int n_in,
                              void* d_out, int out_size, void* d_ws, size_t ws_size,
                              hipStream_t stream) {
  const float* lat = (const float*)d_in[0];
  const float* cb = (const float*)d_in[1];
  float* out = (float*)d_out;
  char* ws = (char*)d_ws;
  unsigned short* cbimg = (unsigned short*)ws;     // 512 KB  (bf16 -2c image)
  float* cnorm = (float*)(ws + 524288);            // 4 KB
  int* idxbuf = (int*)(ws + 528384);               // 256 KB
  float* partial = (float*)(ws + 790528);          // 4 KB (1024 floats)

  vq_prep<<<1024, 256, 0, stream>>>(cb, cbimg, cnorm);
  vq_main<<<256, 512, 0, stream>>>(lat, (const short8*)cbimg, cnorm, idxbuf, partial);
  vq_gather<<<1024, 256, 0, stream>>>(cb, idxbuf, out);
  vq_fin<<<1, 256, 0, stream>>>(partial, out + 16777216);
}